// Round 1
// 592.391 us; speedup vs baseline: 1.0766x; 1.0766x over previous
//
#include <hip/hip_runtime.h>
#include <hip/hip_bf16.h>

// MSA: B=8,S=4096,D=1024,H=16,DH=64. Softmax over HEAD axis per token (16x16).
// Pipeline: convert->fp16, fused QKV GEMM (N=3072), MFMA per-token attention
// (LDS-staged V, dense ctx output), out GEMM (dense A, LDA=1024).
//
// GEMM = 256x256 tile, BK=64, 8 waves (2Mx4N), deep-pipe:
//   - T2 swizzle: LDS byte ^= ((row&7)<<4); applied on global source for
//     global_load_lds (linear LDS dest) and on ds_read_b128 frag reads.
//   - 2-tile lookahead in 2 buffers: all frags of buffer b are register-read
//     at tile start; after one raw s_barrier the buffer is dead chip-wide,
//     so tile t+2 stages into it while tile t's second MFMA half runs.
//   - counted s_waitcnt vmcnt(8) once per tile (never 0 in main loop).
//   - s_setprio(1) around the post-barrier MFMA cluster.
//   - bijective XCD blockIdx swizzle (grid % 8 == 0 for both GEMMs).

#define DEV static __device__ __forceinline__

typedef __attribute__((ext_vector_type(8))) _Float16 fp16x8;
typedef __attribute__((ext_vector_type(4))) float f32x4;

DEV unsigned short f2h(float f) {
    union { _Float16 h; unsigned short u; } c;
    c.h = (_Float16)f;
    return c.u;
}

DEV void gl_lds16(const void* g, void* l) {
    __builtin_amdgcn_global_load_lds(
        (const __attribute__((address_space(1))) unsigned int*)g,
        (__attribute__((address_space(3))) unsigned int*)l, 16, 0, 0);
}

// ---------------- kernel 0: fp32 -> fp16 conversion / packing ----------------
__global__ __launch_bounds__(256) void k_convert(
    const float* __restrict__ x,
    const float* __restrict__ wq, const float* __restrict__ wk,
    const float* __restrict__ wv, const float* __restrict__ wo,
    const float* __restrict__ bq, const float* __restrict__ bk,
    const float* __restrict__ bv,
    unsigned short* __restrict__ Xb, unsigned short* __restrict__ Wb,
    unsigned short* __restrict__ Wob, float* __restrict__ biasc)
{
    const int NX = 33554432 / 4;   // x float4 chunks
    const int NW = 3145728 / 4;    // wq+wk+wv chunks (262144 each)
    const int NO = 1048576 / 4;    // wo chunks
    const int NB = 3072 / 4;       // bias chunks (256 each)
    const int total = NX + NW + NO + NB;
    for (int c = blockIdx.x * blockDim.x + threadIdx.x; c < total;
         c += gridDim.x * blockDim.x) {
        if (c < NX) {
            float4 v = ((const float4*)x)[c];
            uint2 u;
            u.x = f2h(v.x) | ((unsigned int)f2h(v.y) << 16);
            u.y = f2h(v.z) | ((unsigned int)f2h(v.w) << 16);
            ((uint2*)Xb)[c] = u;
        } else if (c < NX + NW) {
            int e = c - NX;
            const float* w = (e < 262144) ? wq : (e < 524288) ? wk : wv;
            int off = e & 262143;
            float4 v = ((const float4*)w)[off];
            uint2 u;
            u.x = f2h(v.x) | ((unsigned int)f2h(v.y) << 16);
            u.y = f2h(v.z) | ((unsigned int)f2h(v.w) << 16);
            ((uint2*)Wb)[e] = u;
        } else if (c < NX + NW + NO) {
            int e = c - NX - NW;
            float4 v = ((const float4*)wo)[e];
            uint2 u;
            u.x = f2h(v.x) | ((unsigned int)f2h(v.y) << 16);
            u.y = f2h(v.z) | ((unsigned int)f2h(v.w) << 16);
            ((uint2*)Wob)[e] = u;
        } else {
            int e = c - NX - NW - NO;               // 0..767
            const float* b = (e < 256) ? bq : (e < 512) ? bk : bv;
            int off = e & 255;
            ((float4*)biasc)[e] = ((const float4*)b)[off];
        }
    }
}

// ---------------- GEMM: C[M][N] = A[M][K] * B[N][K]^T + bias, K=1024 --------
// Per-tile body. MODE 0: stage tile t+2 + vmcnt(8); MODE 1: no stage,
// vmcnt(0) (tile NT-2); MODE 2: last tile, no end barrier.
template <int MODE>
DEV void g256_tile(const unsigned short* __restrict__ Ac,
                   const unsigned short* __restrict__ Bc,
                   unsigned short* As_stg, unsigned short* Bs_stg,
                   const unsigned short* gA, const unsigned short* gB,
                   int tid, int rA, int rB, int c0, int c1,
                   f32x4 (&acc)[8][4])
{
    // k-half 0 frags (swizzled column c0)
    fp16x8 a0[8], b0[4];
#pragma unroll
    for (int i = 0; i < 8; ++i)
        a0[i] = *(const fp16x8*)(const void*)&Ac[rA + i * 1024 + c0];
#pragma unroll
    for (int j = 0; j < 4; ++j)
        b0[j] = *(const fp16x8*)(const void*)&Bc[rB + j * 1024 + c0];
#pragma unroll
    for (int i = 0; i < 8; ++i)
#pragma unroll
        for (int j = 0; j < 4; ++j)
            acc[i][j] = __builtin_amdgcn_mfma_f32_16x16x32_f16(a0[i], b0[j], acc[i][j], 0, 0, 0);

    // k-half 1 frags (swizzled column c1) — must complete before barrier,
    // after which this buffer is overwritten by staging.
    fp16x8 a1[8], b1[4];
#pragma unroll
    for (int i = 0; i < 8; ++i)
        a1[i] = *(const fp16x8*)(const void*)&Ac[rA + i * 1024 + c1];
#pragma unroll
    for (int j = 0; j < 4; ++j)
        b1[j] = *(const fp16x8*)(const void*)&Bc[rB + j * 1024 + c1];

    asm volatile("s_waitcnt lgkmcnt(0)" ::: "memory");
    __builtin_amdgcn_sched_barrier(0);
    __builtin_amdgcn_s_barrier();          // buffer (Ac,Bc) dead chip-wide
    asm volatile("" ::: "memory");

    if (MODE == 0) {
        // stage tile t+2 into the just-freed buffer (8 x global_load_lds 16B)
#pragma unroll
        for (int s = 0; s < 4; ++s) {
            gl_lds16(gA + (size_t)s * 65536, (char*)As_stg + (tid + s * 512) * 16);
            gl_lds16(gB + (size_t)s * 65536, (char*)Bs_stg + (tid + s * 512) * 16);
        }
        __builtin_amdgcn_sched_barrier(0); // pin staging issue before MFMA
    }

    __builtin_amdgcn_s_setprio(1);
#pragma unroll
    for (int i = 0; i < 8; ++i)
#pragma unroll
        for (int j = 0; j < 4; ++j)
            acc[i][j] = __builtin_amdgcn_mfma_f32_16x16x32_f16(a1[i], b1[j], acc[i][j], 0, 0, 0);
    __builtin_amdgcn_s_setprio(0);

    if (MODE == 0) asm volatile("s_waitcnt vmcnt(8)" ::: "memory"); // t+1 landed
    if (MODE == 1) asm volatile("s_waitcnt vmcnt(0)" ::: "memory"); // last tile landed
    if (MODE != 2) {
        __builtin_amdgcn_s_barrier();
        asm volatile("" ::: "memory");
    }
}

template <bool OUT_F16>
__global__ __launch_bounds__(512, 2) void k_gemm256(
    const unsigned short* __restrict__ A,   // [M][1024] fp16
    const unsigned short* __restrict__ B,   // [N][1024] fp16
    const float* __restrict__ bias,         // [N] fp32
    unsigned short* __restrict__ Ch,        // fp16 out (if OUT_F16)
    float* __restrict__ Cf,                 // fp32 out (else)
    int ldc, int nbx)                       // nbx = N/256
{
    __shared__ __align__(16) unsigned short As[2][256 * 64];
    __shared__ __align__(16) unsigned short Bs[2][256 * 64];

    const int tid  = threadIdx.x;
    const int lane = tid & 63;
    const int w    = tid >> 6;
    const int wr   = w >> 2, wc = w & 3;       // 2M x 4N waves
    const int quad = lane >> 4;
    const int lr   = lane & 15;

    // bijective XCD swizzle (gridDim.x % 8 == 0 for both launches)
    const int cpx = gridDim.x >> 3;
    const int id  = (blockIdx.x & 7) * cpx + (blockIdx.x >> 3);
    const int by  = id / nbx, bx = id - by * nbx;
    const int m0  = by * 256, n0 = bx * 256;

    // staging: thread covers rows srow+s*64, fixed swizzled k-offset kk.
    // LDS dest is linear (tid+s*512)*16B; source column pre-swizzled so that
    // LDS position (row, col) holds logical element (row, col ^ ((row&7)*8)).
    const int srow = tid >> 3;
    const int kk   = (((tid & 7) ^ (srow & 7)) << 3);
    const unsigned short* gAp = A + (size_t)(m0 + srow) * 1024 + kk;
    const unsigned short* gBp = B + (size_t)(n0 + srow) * 1024 + kk;

    // frag read bases: row = (wbase + i*16 + lr); (row&7) == (lr&7)
    const int swz = (lr & 7) << 3;
    const int c0  = (quad * 8) ^ swz;
    const int c1  = c0 ^ 32;
    const int rA  = (wr * 128 + lr) * 64;
    const int rB  = (wc * 64 + lr) * 64;

    f32x4 acc[8][4];
#pragma unroll
    for (int i = 0; i < 8; ++i)
#pragma unroll
        for (int j = 0; j < 4; ++j) {
            f32x4 z = {0.f, 0.f, 0.f, 0.f};
            acc[i][j] = z;
        }

    // prologue: stage tiles 0 and 1; vmcnt(8) -> tile 0 landed
#pragma unroll
    for (int s = 0; s < 4; ++s) {
        gl_lds16(gAp + (size_t)s * 65536, (char*)As[0] + (tid + s * 512) * 16);
        gl_lds16(gBp + (size_t)s * 65536, (char*)Bs[0] + (tid + s * 512) * 16);
    }
#pragma unroll
    for (int s = 0; s < 4; ++s) {
        gl_lds16(gAp + (size_t)s * 65536 + 64, (char*)As[1] + (tid + s * 512) * 16);
        gl_lds16(gBp + (size_t)s * 65536 + 64, (char*)Bs[1] + (tid + s * 512) * 16);
    }
    asm volatile("s_waitcnt vmcnt(8)" ::: "memory");
    __builtin_amdgcn_s_barrier();
    asm volatile("" ::: "memory");

    // main loop: 16 K-tiles of 64; tile t stages tile t+2
    const unsigned short* gAt = gAp + 128;   // k0 = 128 (tile 2), col kk folded
    const unsigned short* gBt = gBp + 128;
    for (int t = 0; t < 14; t += 2) {
        g256_tile<0>(As[0], Bs[0], As[0], Bs[0], gAt, gBt, tid, rA, rB, c0, c1, acc);
        gAt += 64; gBt += 64;
        g256_tile<0>(As[1], Bs[1], As[1], Bs[1], gAt, gBt, tid, rA, rB, c0, c1, acc);
        gAt += 64; gBt += 64;
    }
    g256_tile<1>(As[0], Bs[0], As[0], Bs[0], gAt, gBt, tid, rA, rB, c0, c1, acc); // t=14
    g256_tile<2>(As[1], Bs[1], As[1], Bs[1], gAt, gBt, tid, rA, rB, c0, c1, acc); // t=15

    // epilogue: C layout col=lane&15, row=quad*4+r
    float bj[4];
#pragma unroll
    for (int j = 0; j < 4; ++j) bj[j] = bias[n0 + wc * 64 + j * 16 + lr];
#pragma unroll
    for (int i = 0; i < 8; ++i) {
        const int mrow = m0 + wr * 128 + i * 16 + quad * 4;
#pragma unroll
        for (int j = 0; j < 4; ++j) {
            const int ncol = n0 + wc * 64 + j * 16 + lr;
#pragma unroll
            for (int r = 0; r < 4; ++r) {
                float v = acc[i][j][r] + bj[j];
                if (OUT_F16)
                    Ch[(size_t)(mrow + r) * ldc + ncol] = f2h(v);
                else
                    Cf[(size_t)(mrow + r) * ldc + ncol] = v;
            }
        }
    }
}

// ---------------- kernel 2: per-token 16x16 head attention via MFMA ---------
// One wave per token. qkv row = [q(1024)|k(1024)|v(1024)] fp16 (read-only).
// All global traffic coalesced uint4: 6 loads + 2 stores per lane.
// scores(16x16) = Q K^T : 2 mfma_16x16x32_f16 (frags from padded LDS rows).
// softmax over g: 16-lane butterfly shuffles in C layout.
// ctx(16x64) = P(16x16) V : 4 mfma; V transposed into LDS at stage time so
// B-frags are contiguous ds_read_b128. ctx repacked via LDS -> dense Ctx.
__global__ __launch_bounds__(256) void k_attn(
    const unsigned short* __restrict__ qkv,
    unsigned short* __restrict__ Ctx)           // [32768][1024] fp16
{
    __shared__ __align__(16) unsigned short sqk[4][32 * 72];
    __shared__ __align__(16) unsigned short svt[4][64 * 24];
    __shared__ __align__(16) unsigned short spp[4][16 * 24];

    const int tid  = threadIdx.x;
    const int wv   = tid >> 6;
    const int l    = tid & 63;
    const int t    = blockIdx.x * 4 + wv;
    const unsigned short* tok = qkv + (size_t)t * 3072;

    unsigned short* qk = sqk[wv];
    unsigned short* vt = svt[wv];
    unsigned short* pp = spp[wv];

    const int quad = l >> 4;
    const int lr   = l & 15;
    const int row8 = l >> 3;          // 0..7
    const int col8 = (l & 7) * 8;     // 0,8,..,56

#pragma unroll
    for (int i = 0; i < 4; ++i) {
        const int row = i * 8 + row8;
        uint4 u = *(const uint4*)(tok + i * 512 + l * 8);
        *(uint4*)&qk[row * 72 + col8] = u;
    }
#pragma unroll
    for (int i = 0; i < 2; ++i) {
        const int g = i * 8 + row8;
        uint4 u = *(const uint4*)(tok + 2048 + i * 512 + l * 8);
        const unsigned short* hu = (const unsigned short*)&u;
#pragma unroll
        for (int c = 0; c < 8; ++c)
            vt[(col8 + c) * 24 + g] = hu[c];
    }
    asm volatile("s_waitcnt lgkmcnt(0)" ::: "memory");

    f32x4 s = {0.f, 0.f, 0.f, 0.f};
#pragma unroll
    for (int ks = 0; ks < 2; ++ks) {
        fp16x8 aq = *(const fp16x8*)(const void*)&qk[lr * 72 + ks * 32 + quad * 8];
        fp16x8 bk = *(const fp16x8*)(const void*)&qk[(16 + lr) * 72 + ks * 32 + quad * 8];
        s = __builtin_amdgcn_mfma_f32_16x16x32_f16(aq, bk, s, 0, 0, 0);
    }

#pragma unroll
    for (int r = 0; r < 4; ++r) {
        float sv = s[r] * 0.125f;          // 1/sqrt(64)
        float m = sv;
        m = fmaxf(m, __shfl_xor(m, 1, 64));
        m = fmaxf(m, __shfl_xor(m, 2, 64));
        m = fmaxf(m, __shfl_xor(m, 4, 64));
        m = fmaxf(m, __shfl_xor(m, 8, 64));
        float e = __expf(sv - m);
        float su = e;
        su += __shfl_xor(su, 1, 64);
        su += __shfl_xor(su, 2, 64);
        su += __shfl_xor(su, 4, 64);
        su += __shfl_xor(su, 8, 64);
        float p = e * __builtin_amdgcn_rcpf(su);
        pp[(quad * 4 + r) * 24 + lr] = f2h(p);   // P[h][g]
    }
    asm volatile("s_waitcnt lgkmcnt(0)" ::: "memory");

    fp16x8 pa;
    if (quad < 2) {
        pa = *(const fp16x8*)(const void*)&pp[lr * 24 + quad * 8];
    } else {
#pragma unroll
        for (int j = 0; j < 8; ++j) pa[j] = (_Float16)0.f;
    }

    f32x4 c[4];
#pragma unroll
    for (int nb = 0; nb < 4; ++nb) {
        fp16x8 bv;
        if (quad < 2) {
            bv = *(const fp16x8*)(const void*)&vt[(nb * 16 + lr) * 24 + quad * 8];
        } else {
#pragma unroll
            for (int j = 0; j < 8; ++j) bv[j] = (_Float16)0.f;
        }
        f32x4 z = {0.f, 0.f, 0.f, 0.f};
        c[nb] = __builtin_amdgcn_mfma_f32_16x16x32_f16(pa, bv, z, 0, 0, 0);
    }
    asm volatile("s_waitcnt lgkmcnt(0)" ::: "memory");

#pragma unroll
    for (int nb = 0; nb < 4; ++nb)
#pragma unroll
        for (int r = 0; r < 4; ++r)
            qk[(quad * 4 + r) * 72 + nb * 16 + lr] = f2h(c[nb][r]);
    asm volatile("s_waitcnt lgkmcnt(0)" ::: "memory");

    unsigned short* dst = Ctx + (size_t)t * 1024;
#pragma unroll
    for (int i = 0; i < 2; ++i) {
        const int row = i * 8 + row8;
        uint4 u = *(const uint4*)&qk[row * 72 + col8];
        *(uint4*)(dst + row * 64 + col8) = u;
    }
}

// ---------------- launch ----------------------------------------------------
extern "C" void kernel_launch(void* const* d_in, const int* in_sizes, int n_in,
                              void* d_out, int out_size, void* d_ws, size_t ws_size,
                              hipStream_t stream)
{
    (void)in_sizes; (void)n_in; (void)out_size;

    const float* x  = (const float*)d_in[0];
    const float* wq = (const float*)d_in[1];
    const float* bq = (const float*)d_in[2];
    const float* wk = (const float*)d_in[3];
    const float* bk = (const float*)d_in[4];
    const float* wv = (const float*)d_in[5];
    const float* bv = (const float*)d_in[6];
    const float* wo = (const float*)d_in[7];
    const float* bo = (const float*)d_in[8];

    // ws layout (bytes):
    //   QKV  [32768][3072] fp16 : 0          .. 201326592   (192 MiB)
    //   Xb   [32768][1024] fp16 : 201326592  .. 268435456   ( 64 MiB)
    //        (reused as dense Ctx after the QKV GEMM has consumed it)
    //   Wb   [3072][1024]  fp16 : 268435456  .. 274726912   (  6 MiB)
    //   Wob  [1024][1024]  fp16 : 274726912  .. 276824064   (  2 MiB)
    //   bias [3072]        fp32 : 276824064  .. 276836352   ( 12 KiB)
    if (ws_size < 276836352ull) return;

    char* ws = (char*)d_ws;
    unsigned short* QKV  = (unsigned short*)(ws);
    unsigned short* Xb   = (unsigned short*)(ws + 201326592);
    unsigned short* Wb   = (unsigned short*)(ws + 268435456);
    unsigned short* Wob  = (unsigned short*)(ws + 274726912);
    float*          bqkv = (float*)(ws + 276824064);
    unsigned short* Ctx  = Xb;   // Xb dead after QKV GEMM (stream-ordered)

    k_convert<<<2048, 256, 0, stream>>>(x, wq, wk, wv, wo, bq, bk, bv,
                                        Xb, Wb, Wob, bqkv);
    // QKV GEMM: M=32768, N=3072 -> 128x12 = 1536 blocks (%8==0)
    k_gemm256<true><<<1536, 512, 0, stream>>>(
        Xb, Wb, bqkv, QKV, nullptr, 3072, 12);
    k_attn<<<8192, 256, 0, stream>>>(QKV, Ctx);
    // out GEMM: M=32768, N=1024 -> 128x4 = 512 blocks (%8==0)
    k_gemm256<false><<<512, 512, 0, stream>>>(
        Ctx, Wob, bo, nullptr, (float*)d_out, 1024, 4);
}